// Round 10
// baseline (533.538 us; speedup 1.0000x reference)
//
#include <hip/hip_runtime.h>
#include <stdint.h>

// ---------------------------------------------------------------------------
// TimeAwareIMULSTMEncoder on MI355X (gfx950) — round 10
// vs round 9 (r5 structure kept; scan re-tiled for cross-block overlap):
//  * k_scan: 5 seqs/block, 512 blocks total = 2 blocks/CU on all 256 CUs
//    (was 16 seqs, 160 blocks on 160 CUs). Four scan variants (r4/r5/r9)
//    all pinned at 74-80 us -> bound is per-CU issue + same-block barrier
//    serialization. 2 independent blocks/CU overlap barrier stalls (m114);
//    256 CUs cut per-CU pointwise 1.6x. LDS 19 KB/block, 44 VGPR < 64 cap.
//  * prefetch reverted to depth-1 (depth-2 regressed: 74.4 -> 80.3 us).
// ---------------------------------------------------------------------------

typedef unsigned short ushort_t;
typedef short short8 __attribute__((ext_vector_type(8)));     // 8 bf16 (4 VGPRs)
typedef float float4v __attribute__((ext_vector_type(4)));    // MFMA acc

#define DEV_INLINE __device__ __forceinline__

DEV_INLINE ushort_t f2bf(float f) {                 // RNE f32 -> bf16 bits
  union { float f; unsigned u; } v; v.f = f;
  unsigned r = v.u + 0x7fffu + ((v.u >> 16) & 1u);
  return (ushort_t)(r >> 16);
}
DEV_INLINE float bf2f(ushort_t s) {
  union { unsigned u; float f; } v; v.u = ((unsigned)s) << 16;
  return v.f;
}
DEV_INLINE float sigmoidf_(float x) {
  return __builtin_amdgcn_rcpf(1.0f + __expf(-x));
}
DEV_INLINE float tanhf_(float x) {                  // 1 - 2/(1+e^{2x}); safe at +-inf
  return 1.0f - 2.0f * __builtin_amdgcn_rcpf(1.0f + __expf(2.0f * x));
}

// async global->LDS, 16B per lane; dst must be wave-uniform base + lane*16.
DEV_INLINE void gload16(const ushort_t* g, ushort_t* l) {
  __builtin_amdgcn_global_load_lds(
      (const __attribute__((address_space(1))) unsigned int*)g,
      (__attribute__((address_space(3))) unsigned int*)l, 16, 0, 0);
}

// --------------------------- weight prep (tiled transpose) ------------------
__global__ __launch_bounds__(256) void k_prep(
    const float* __restrict__ Wih0, const float* __restrict__ Wih1,
    const float* __restrict__ Wih2, const float* __restrict__ Whh0,
    const float* __restrict__ Whh1, const float* __restrict__ Whh2,
    const float* __restrict__ Wout1, const float* __restrict__ Wout2,
    ushort_t* __restrict__ WT)
{
  __shared__ float T[32][65];
  const int b = blockIdx.x;
  const int tid = threadIdx.x;
  const float* S; int Kd, C; size_t dstBase; int kt, nt;
  if (b < 32) {
    int rel = b; int d = (rel >> 3) / 2; kt = (rel >> 3) & 1; nt = rel & 7;
    S = Wih0 + (size_t)d * 64 * 512; C = 512; Kd = 64;
    dstBase = 0 + (size_t)d * 512 * 64;
  } else if (b < 160) {
    int rel = b - 32; int d = (rel >> 3) / 8; kt = (rel >> 3) & 7; nt = rel & 7;
    S = Wih1 + (size_t)d * 256 * 512; C = 512; Kd = 256;
    dstBase = 65536 + (size_t)d * 512 * 256;
  } else if (b < 288) {
    int rel = b - 160; int d = (rel >> 3) / 8; kt = (rel >> 3) & 7; nt = rel & 7;
    S = Wih2 + (size_t)d * 256 * 512; C = 512; Kd = 256;
    dstBase = 327680 + (size_t)d * 512 * 256;
  } else if (b < 352) {
    int rel = b - 288; int d = (rel >> 3) / 4; kt = (rel >> 3) & 3; nt = rel & 7;
    S = Whh0 + (size_t)d * 128 * 512; C = 512; Kd = 128;
    dstBase = 589824 + (size_t)d * 512 * 128;
  } else if (b < 416) {
    int rel = b - 352; int d = (rel >> 3) / 4; kt = (rel >> 3) & 3; nt = rel & 7;
    S = Whh1 + (size_t)d * 128 * 512; C = 512; Kd = 128;
    dstBase = 720896 + (size_t)d * 512 * 128;
  } else if (b < 480) {
    int rel = b - 416; int d = (rel >> 3) / 4; kt = (rel >> 3) & 3; nt = rel & 7;
    S = Whh2 + (size_t)d * 128 * 512; C = 512; Kd = 128;
    dstBase = 851968 + (size_t)d * 512 * 128;
  } else if (b < 672) {
    int rel = b - 480; kt = rel >> 3; nt = rel & 7;
    S = Wout1; C = 512; Kd = 768; dstBase = 983040;
  } else {
    int rel = b - 672; kt = rel >> 2; nt = rel & 3;
    S = Wout2; C = 256; Kd = 512; dstBase = 1376256;
  }
  const int k0 = kt * 32, n0 = nt * 64;
  {
    int kr = tid >> 6;                // 0..3
    int n  = tid & 63;
#pragma unroll
    for (int i = 0; i < 8; i++)
      T[i * 4 + kr][n] = S[(size_t)(k0 + i * 4 + kr) * C + n0 + n];
  }
  __syncthreads();
  {
    int n = tid >> 2;                 // 0..63
    int ko = (tid & 3) * 8;           // 0,8,16,24
    ushort_t pk[8];
#pragma unroll
    for (int j = 0; j < 8; j++) pk[j] = f2bf(T[ko + j][n]);
    *(uint4*)(WT + dstBase + (size_t)(n0 + n) * Kd + k0 + ko) = *(uint4*)pk;
  }
}

// --------------------------- input projection ------------------------------
__global__ __launch_bounds__(256) void k_inproj(
    const float* __restrict__ imu, const float* __restrict__ W_in,
    const float* __restrict__ b_in, ushort_t* __restrict__ act0)
{
  int idx = blockIdx.x * 256 + threadIdx.x;   // 64000*64 exactly
  int j = idx & 63, r = idx >> 6;
  int l = r % 50;
  const float* x = imu + (size_t)r * 6;
  float acc = b_in[j];
#pragma unroll
  for (int d = 0; d < 6; d++) acc += x[d] * W_in[d * 64 + j];
  acc += (l * (1.0f / 49.0f)) * W_in[6 * 64 + j] + W_in[7 * 64 + j]; // t, rate=1
  act0[idx] = f2bf(fmaxf(acc, 0.0f));
}

// --------------------------- xg GEMM (bf16 MFMA, 64x256 tile) ---------------
template <int K>
__global__ __launch_bounds__(256, 3) void k_xg_gemm(
    const ushort_t* __restrict__ X,    // [64000][K] bf16 (m-major)
    const ushort_t* __restrict__ WT,   // [2][512][K] bf16 (n-major)
    const float* __restrict__ bih, const float* __restrict__ bhh, // [2][512]
    ushort_t* __restrict__ xg,         // [dirSlot][2][50][1280][256]
    int dirBase)
{
  __shared__ __align__(16) ushort_t As[2][64 * 32];    //  8 KiB
  __shared__ __align__(16) ushort_t Bs[2][256 * 32];   // 32 KiB
  const int dir = blockIdx.z + dirBase;
  const int gp  = blockIdx.y;
  const int m0  = blockIdx.x * 64;
  const int tid = threadIdx.x;
  const int wave = tid >> 6, lane = tid & 63;
  const int cl = lane & 15, quad = lane >> 4;
  const ushort_t* Wd = WT + ((size_t)dir * 512 + gp * 256) * K;   // 256 rows

  float4v acc[4][2][2];
#pragma unroll
  for (int i = 0; i < 4; i++)
#pragma unroll
    for (int u = 0; u < 2; u++)
#pragma unroll
      for (int q = 0; q < 2; q++) acc[i][u][q] = float4v{0.f, 0.f, 0.f, 0.f};

  const int srow = lane >> 2;         // 0..15
  const int scol = (lane & 3) * 8;    // 0,8,16,24

#define STAGE(buf, kb)                                                        \
  {                                                                           \
    gload16(X + (size_t)(m0 + wave * 16 + srow) * K + (kb) + scol,            \
            &As[buf][wave * 16 * 32] + lane * 8);                             \
    _Pragma("unroll")                                                         \
    for (int j = 0; j < 4; j++)                                               \
      gload16(Wd + (size_t)(wave * 64 + j * 16 + srow) * K + (kb) + scol,     \
              &Bs[buf][(wave * 64 + j * 16) * 32] + lane * 8);                \
  }

  STAGE(0, 0)
  for (int kb = 0; kb < K; kb += 32) {
    const int cur = (kb >> 5) & 1;
    __syncthreads();                  // drains DMA for cur; protects cur^1 reuse
    if (kb + 32 < K) STAGE(cur ^ 1, kb + 32)
    short8 Af[4], Bf[2][2];
#pragma unroll
    for (int i = 0; i < 4; i++)
      Af[i] = *(const short8*)(&As[cur][(i * 16 + cl) * 32 + quad * 8]);
#pragma unroll
    for (int u = 0; u < 2; u++)
#pragma unroll
      for (int q = 0; q < 2; q++)
        Bf[u][q] = *(const short8*)(&Bs[cur][(q * 128 + wave * 32 + u * 16 + cl) * 32 + quad * 8]);
#pragma unroll
    for (int i = 0; i < 4; i++)
#pragma unroll
      for (int u = 0; u < 2; u++)
#pragma unroll
        for (int q = 0; q < 2; q++)
          acc[i][u][q] = __builtin_amdgcn_mfma_f32_16x16x32_bf16(Af[i], Bf[u][q], acc[i][u][q], 0, 0, 0);
  }
#undef STAGE

  ushort_t* outp = xg + (size_t)blockIdx.z * 32768000ull + (size_t)gp * 16384000ull;
  const int gbase = dir * 512 + gp * 256;
#pragma unroll
  for (int u = 0; u < 2; u++) {
    const int hc = wave * 32 + u * 16 + cl;
    float b0 = bih[gbase + hc] + bhh[gbase + hc];
    float b1 = bih[gbase + 128 + hc] + bhh[gbase + 128 + hc];
#pragma unroll
    for (int i = 0; i < 4; i++) {
#pragma unroll
      for (int r = 0; r < 4; r++) {
        int m = m0 + i * 16 + quad * 4 + r;   // D: row=quad*4+r, col=lane&15
        int seq = m / 50, t = m - seq * 50;
        unsigned pk = (unsigned)f2bf(acc[i][u][0][r] + b0) |
                      ((unsigned)f2bf(acc[i][u][1][r] + b1) << 16);
        *(unsigned*)(outp + ((size_t)t * 1280 + seq) * 256 + hc * 2) = pk;
      }
    }
  }
}

// --------------------------- LSTM scan (round 10) ---------------------------
// One block = 5 seqs of one direction, 1024 thr / 16 waves; 512 blocks =
// 2 blocks/CU (barrier stalls of the two independent blocks overlap).
// Phase 1: wave (gp=w>>3, hg=w&7) computes gates {gp*2,gp*2+1} for hcols
//          hg*16+cl via 8 MFMAs (Whh frags in VGPRs); P exchange in LDS.
// Phase 2: 640 cells, lanes tid<640 do 1 cell each (wave-uniform skip).
template <int MODE>
__global__ __launch_bounds__(1024, 8) void k_scan(
    const ushort_t* __restrict__ xg,    // [dirSlot][2][50][1280][256]
    const ushort_t* __restrict__ WhhT,  // [2][512][128] bf16 n-major
    ushort_t* __restrict__ Y,           // [64000][256] bf16
    ushort_t* __restrict__ aggb,        // [1280][768] bf16
    int dirBase)
{
  const int dir = blockIdx.y + dirBase;
  const int s0 = blockIdx.x * 5;
  const int tid = threadIdx.x;
  const int wave = tid >> 6, lane = tid & 63;
  const int cl = lane & 15, quad = lane >> 4;
  const int gp = wave >> 3;             // gate pair: 0=(i,f) 1=(g,o)
  const int hcolw = (wave & 7) * 16 + cl;

  __shared__ __align__(16) ushort_t hbuf[2][16][136];   // 8.5 KiB (rows 5..15 stay 0)
  __shared__ __align__(16) float P0[640 * 2];           // 5 KiB (i,f sums)
  __shared__ __align__(16) float P1[640 * 2];           // 5 KiB (g,o sums)

  // Whh^T fragments for this wave's 2 gates: 2 x 4 x short8 = 32 VGPR
  short8 Bf[2][4];
  const ushort_t* WTd = WhhT + (size_t)dir * (512 * 128);
#pragma unroll
  for (int q = 0; q < 2; q++)
#pragma unroll
    for (int kt = 0; kt < 4; kt++)
      Bf[q][kt] = *(const short8*)(WTd + ((gp * 2 + q) * 128 + hcolw) * 128 + kt * 32 + quad * 8);

  const int cseq = tid >> 7, chcol = tid & 127;   // cell for tid < 640
  const bool own = tid < 640;

  float cst = 0.f, sum = 0.f, mx = -3.0e38f, hLast = 0.f;
  ushort_t pend = 0;
  int tPrev = 0;

  for (int i = tid; i < 2 * 16 * 136; i += 1024) ((ushort_t*)hbuf)[i] = 0;

  const ushort_t* xgp = xg + (size_t)blockIdx.y * 32768000ull;
  const int t0 = dir ? 49 : 0;

  unsigned xifC = 0, xgoC = 0, xifN = 0, xgoN = 0;
  if (own) {
    size_t base = ((size_t)t0 * 1280 + s0 + cseq) * 256 + chcol * 2;
    xifC = *(const unsigned*)(xgp + base);
    xgoC = *(const unsigned*)(xgp + 16384000u + base);
  }
  __syncthreads();                      // hbuf zero visible

  for (int step = 0; step < 50; step++) {
    const int t = dir ? (49 - step) : step;
    const int cur = step & 1;

    // ---- phase 1 ----
    if (own && step < 49) {             // next step's x -> VGPRs
      const int tn = dir ? (t - 1) : (t + 1);
      size_t base = ((size_t)tn * 1280 + s0 + cseq) * 256 + chcol * 2;
      xifN = *(const unsigned*)(xgp + base);
      xgoN = *(const unsigned*)(xgp + 16384000u + base);
    }
    if (MODE == 0 && own && step > 0)   // flush previous step's Y
      Y[((size_t)(s0 + cseq) * 50 + tPrev) * 256 + dir * 128 + chcol] = pend;

    short8 Af[4];
#pragma unroll
    for (int kt = 0; kt < 4; kt++)      // A: m=lane&15, k=quad*8+j
      Af[kt] = *(const short8*)(&hbuf[cur][cl][kt * 32 + quad * 8]);

    float4v acc[2];
#pragma unroll
    for (int q = 0; q < 2; q++) acc[q] = float4v{0.f, 0.f, 0.f, 0.f};
#pragma unroll
    for (int kt = 0; kt < 4; kt++)
#pragma unroll
      for (int q = 0; q < 2; q++)
        acc[q] = __builtin_amdgcn_mfma_f32_16x16x32_bf16(Af[kt], Bf[q][kt], acc[q], 0, 0, 0);

    float* Pg = gp ? P1 : P0;
#pragma unroll
    for (int r = 0; r < 4; r++) {
      int seq = quad * 4 + r;           // C: row=quad*4+r, col=lane&15
      if (seq < 5)
        *(float2*)(Pg + (seq * 128 + hcolw) * 2) = make_float2(acc[0][r], acc[1][r]);
    }
    __syncthreads();                    // gate sums visible

    // ---- phase 2 ----
    if (own) {
      float2 a0 = *(const float2*)(P0 + tid * 2);
      float2 a1 = *(const float2*)(P1 + tid * 2);
      float gi = a0.x + bf2f((ushort_t)(xifC & 0xffff));
      float gf = a0.y + bf2f((ushort_t)(xifC >> 16));
      float gg = a1.x + bf2f((ushort_t)(xgoC & 0xffff));
      float go = a1.y + bf2f((ushort_t)(xgoC >> 16));
      float ii = sigmoidf_(gi);
      float ff = sigmoidf_(gf);
      float gc = tanhf_(gg);
      float oo = sigmoidf_(go);
      float c2 = ff * cst + ii * gc;
      cst = c2;
      float h = oo * tanhf_(c2);
      ushort_t hb = f2bf(h);
      hbuf[cur ^ 1][cseq][chcol] = hb;
      if (MODE == 0) {
        pend = hb;
      } else {
        sum += h;
        mx = fmaxf(mx, h);
        hLast = h;
      }
    }
    tPrev = t;
    __syncthreads();                    // h visible; P reusable
    xifC = xifN; xgoC = xgoN;
  }

  if (MODE == 0) {
    if (own)
      Y[((size_t)(s0 + cseq) * 50 + tPrev) * 256 + dir * 128 + chcol] = pend;
  } else if (own) {
    const int seq = s0 + cseq;
    const int c = dir * 128 + chcol;
    aggb[(size_t)seq * 768 + c]       = f2bf(sum * (1.0f / 50.0f));
    aggb[(size_t)seq * 768 + 256 + c] = f2bf(mx);
    aggb[(size_t)seq * 768 + 512 + c] = f2bf(hLast);   // h_n of this dir
  }
}

// --------------------------- fused head -------------------------------------
__global__ __launch_bounds__(512, 1) void k_head(
    const ushort_t* __restrict__ aggb,  // [1280][768] bf16
    const ushort_t* __restrict__ W1T,   // [512][768] bf16
    const float* __restrict__ b1, const float* __restrict__ ln_g,
    const float* __restrict__ ln_b,
    const ushort_t* __restrict__ W2T,   // [256][512] bf16
    const float* __restrict__ b2, float* __restrict__ out) // [1280][256]
{
  __shared__ __align__(16) char smem[78336];
  ushort_t* AsB = (ushort_t*)smem;            // [2][64*32]   (8 KiB)
  ushort_t* BsB = (ushort_t*)(smem + 8192);   // [2][512*32]  (64 KiB)
  ushort_t* hn  = (ushort_t*)smem;            // [64][520] aliased (66.6 KiB)
  float* partS  = (float*)(smem + 73728);     // [64][8]
  float* partQ  = partS + 512;                // [64][8]
  float* muS    = partQ + 512;                // [64]
  float* rsS    = muS + 64;                   // [64]

  const int m0 = blockIdx.x * 64;
  const int tid = threadIdx.x;
  const int wave = tid >> 6, lane = tid & 63;
  const int cl = lane & 15, quad = lane >> 4;
  const int srow = lane >> 2, scol = (lane & 3) * 8;

  float4v acc1[4][4];
#pragma unroll
  for (int i = 0; i < 4; i++)
#pragma unroll
    for (int v = 0; v < 4; v++) acc1[i][v] = float4v{0.f, 0.f, 0.f, 0.f};

#define STAGE1(buf, kb)                                                       \
  {                                                                           \
    if (wave < 4)                                                             \
      gload16(aggb + (size_t)(m0 + wave * 16 + srow) * 768 + (kb) + scol,     \
              AsB + (buf) * 2048 + wave * 16 * 32 + lane * 8);                \
    _Pragma("unroll")                                                         \
    for (int j = 0; j < 4; j++)                                               \
      gload16(W1T + (size_t)(wave * 64 + j * 16 + srow) * 768 + (kb) + scol,  \
              BsB + (buf) * 16384 + (wave * 64 + j * 16) * 32 + lane * 8);    \
  }

  STAGE1(0, 0)
  for (int kb = 0; kb < 768; kb += 32) {
    const int cur = (kb >> 5) & 1;
    __syncthreads();
    if (kb + 32 < 768) STAGE1(cur ^ 1, kb + 32)
    short8 Af[4], Bf[4];
#pragma unroll
    for (int i = 0; i < 4; i++)
      Af[i] = *(const short8*)(AsB + cur * 2048 + (i * 16 + cl) * 32 + quad * 8);
#pragma unroll
    for (int v = 0; v < 4; v++)
      Bf[v] = *(const short8*)(BsB + cur * 16384 + (wave * 64 + v * 16 + cl) * 32 + quad * 8);
#pragma unroll
    for (int i = 0; i < 4; i++)
#pragma unroll
      for (int v = 0; v < 4; v++)
        acc1[i][v] = __builtin_amdgcn_mfma_f32_16x16x32_bf16(Af[i], Bf[v], acc1[i][v], 0, 0, 0);
  }
#undef STAGE1
  __syncthreads();          // all waves done with AsB/BsB (hn aliases them)

  float bcol[4], lg[4], lb[4];
#pragma unroll
  for (int v = 0; v < 4; v++) {
    int col = wave * 64 + v * 16 + cl;
    bcol[v] = b1[col]; lg[v] = ln_g[col]; lb[v] = ln_b[col];
  }

#pragma unroll
  for (int i = 0; i < 4; i++) {
#pragma unroll
    for (int r = 0; r < 4; r++) {
      float s = 0.f, q = 0.f;
#pragma unroll
      for (int v = 0; v < 4; v++) {
        float x = acc1[i][v][r] + bcol[v];
        s += x; q += x * x;
      }
#pragma unroll
      for (int m = 1; m <= 8; m <<= 1) {
        s += __shfl_xor(s, m);
        q += __shfl_xor(q, m);
      }
      if (cl == 0) {
        int row = i * 16 + quad * 4 + r;
        partS[row * 8 + wave] = s;
        partQ[row * 8 + wave] = q;
      }
    }
  }
  __syncthreads();
  if (tid < 64) {
    float s = 0.f, q = 0.f;
#pragma unroll
    for (int w = 0; w < 8; w++) { s += partS[tid * 8 + w]; q += partQ[tid * 8 + w]; }
    float mu = s * (1.0f / 512.0f);
    float var = q * (1.0f / 512.0f) - mu * mu;
    muS[tid] = mu;
    rsS[tid] = rsqrtf(var + 1e-5f);
  }
  __syncthreads();

#pragma unroll
  for (int i = 0; i < 4; i++) {
#pragma unroll
    for (int r = 0; r < 4; r++) {
      int row = i * 16 + quad * 4 + r;
      float mu = muS[row], rs = rsS[row];
#pragma unroll
      for (int v = 0; v < 4; v++) {
        int col = wave * 64 + v * 16 + cl;
        float x = acc1[i][v][r] + bcol[v];
        float y = (x - mu) * rs * lg[v] + lb[v];
        hn[row * 520 + col] = f2bf(fmaxf(y, 0.0f));
      }
    }
  }
  __syncthreads();

  float4v acc2[4][2];
#pragma unroll
  for (int i = 0; i < 4; i++)
#pragma unroll
    for (int u = 0; u < 2; u++) acc2[i][u] = float4v{0.f, 0.f, 0.f, 0.f};
  for (int kt = 0; kt < 16; kt++) {
    short8 Af2[4], Bf2[2];
#pragma unroll
    for (int u = 0; u < 2; u++)
      Bf2[u] = *(const short8*)(W2T + (size_t)(wave * 32 + u * 16 + cl) * 512 + kt * 32 + quad * 8);
#pragma unroll
    for (int i = 0; i < 4; i++)
      Af2[i] = *(const short8*)(hn + (i * 16 + cl) * 520 + kt * 32 + quad * 8);
#pragma unroll
    for (int i = 0; i < 4; i++)
#pragma unroll
      for (int u = 0; u < 2; u++)
        acc2[i][u] = __builtin_amdgcn_mfma_f32_16x16x32_bf16(Af2[i], Bf2[u], acc2[i][u], 0, 0, 0);
  }
#pragma unroll
  for (int u = 0; u < 2; u++) {
    int col = wave * 32 + u * 16 + cl;
    float bb = b2[col];
#pragma unroll
    for (int i = 0; i < 4; i++)
#pragma unroll
      for (int r = 0; r < 4; r++)
        out[(size_t)(m0 + i * 16 + quad * 4 + r) * 256 + col] = acc2[i][u][r] + bb;
  }
}

// --------------------------- launcher --------------------------------------
extern "C" void kernel_launch(void* const* d_in, const int* in_sizes, int n_in,
                              void* d_out, int out_size, void* d_ws, size_t ws_size,
                              hipStream_t stream)
{
  (void)in_sizes; (void)n_in; (void)out_size;
  const float* imu   = (const float*)d_in[0];
  const float* W_in  = (const float*)d_in[1];
  const float* b_in  = (const float*)d_in[2];
  const float* Wih0  = (const float*)d_in[3];
  const float* Whh0  = (const float*)d_in[4];
  const float* bih0  = (const float*)d_in[5];
  const float* bhh0  = (const float*)d_in[6];
  const float* Wih1  = (const float*)d_in[7];
  const float* Whh1  = (const float*)d_in[8];
  const float* bih1  = (const float*)d_in[9];
  const float* bhh1  = (const float*)d_in[10];
  const float* Wih2  = (const float*)d_in[11];
  const float* Whh2  = (const float*)d_in[12];
  const float* bih2  = (const float*)d_in[13];
  const float* bhh2  = (const float*)d_in[14];
  const float* Wout1 = (const float*)d_in[15];
  const float* bout1 = (const float*)d_in[16];
  const float* ln_g  = (const float*)d_in[17];
  const float* ln_b  = (const float*)d_in[18];
  const float* Wout2 = (const float*)d_in[19];
  const float* bout2 = (const float*)d_in[20];
  float* out = (float*)d_out;
  char* ws = (char*)d_ws;

  // ws layout (bytes)
  const size_t ACT0_OFF = 0;                      // 8,192,000  (64000*64*2)
  const size_t YA_OFF   = 8192000;                // 32,768,000 (64000*256*2)
  const size_t YB_OFF   = 40960000;               // 32,768,000
  const size_t XG_OFF   = 73728000;               // 131,072,000 (both) / 65,536,000 (serial)
  const size_t XG_BOTH  = 131072000, XG_SER = 65536000;
  const size_t WT_SZ    = 3014656;                // 1,507,328 bf16 elems
  const bool both = ws_size >= XG_OFF + XG_BOTH + WT_SZ;
  const size_t WT_OFF = XG_OFF + (both ? XG_BOTH : XG_SER);

  ushort_t* act0 = (ushort_t*)(ws + ACT0_OFF);
  ushort_t* Ya   = (ushort_t*)(ws + YA_OFF);
  ushort_t* Yb   = (ushort_t*)(ws + YB_OFF);
  ushort_t* xg   = (ushort_t*)(ws + XG_OFF);
  ushort_t* WT   = (ushort_t*)(ws + WT_OFF);
  ushort_t* aggb = (ushort_t*)(ws + 0);           // reuses act0 region (dead by then)

  ushort_t* WT_ih0 = WT + 0;
  ushort_t* WT_ih1 = WT + 65536;
  ushort_t* WT_ih2 = WT + 327680;
  ushort_t* WT_hh0 = WT + 589824;
  ushort_t* WT_hh1 = WT + 720896;
  ushort_t* WT_hh2 = WT + 851968;
  ushort_t* W1T    = WT + 983040;
  ushort_t* W2T    = WT + 1376256;

  k_prep<<<736, 256, 0, stream>>>(Wih0, Wih1, Wih2, Whh0, Whh1, Whh2,
                                  Wout1, Wout2, WT);
  k_inproj<<<16000, 256, 0, stream>>>(imu, W_in, b_in, act0);

  const int nPass = both ? 1 : 2;
  const int gz = both ? 2 : 1;

  const ushort_t* Xs[3]   = {act0, Ya, Yb};
  ushort_t* Ys[3]         = {Ya, Yb, Ya};
  const ushort_t* WTih[3] = {WT_ih0, WT_ih1, WT_ih2};
  const ushort_t* WThh[3] = {WT_hh0, WT_hh1, WT_hh2};
  const float* bihs[3]    = {bih0, bih1, bih2};
  const float* bhhs[3]    = {bhh0, bhh1, bhh2};

  for (int layer = 0; layer < 3; layer++) {
    for (int p = 0; p < nPass; p++) {
      int dirBase = both ? 0 : p;
      if (layer == 0)
        k_xg_gemm<64><<<dim3(1000, 2, gz), 256, 0, stream>>>(
            Xs[0], WTih[0], bihs[0], bhhs[0], xg, dirBase);
      else
        k_xg_gemm<256><<<dim3(1000, 2, gz), 256, 0, stream>>>(
            Xs[layer], WTih[layer], bihs[layer], bhhs[layer], xg, dirBase);
      if (layer < 2)
        k_scan<0><<<dim3(256, gz), 1024, 0, stream>>>(xg, WThh[layer], Ys[layer], aggb, dirBase);
      else
        k_scan<1><<<dim3(256, gz), 1024, 0, stream>>>(xg, WThh[layer], Ys[layer], aggb, dirBase);
    }
  }

  k_head<<<20, 512, 0, stream>>>(aggb, W1T, bout1, ln_g, ln_b, W2T, bout2, out);
}